// Round 7
// baseline (1224.256 us; speedup 1.0000x reference)
//
#include <hip/hip_runtime.h>

#define NN 100000
#define NE 600000
#define NG 512
#define D 128
#define NL 3
#define EPS 1e-5f

// ---------------------------------------------------------------------------
// CSR build: histogram -> exclusive scan -> fill (sorted-by-dst source list)
// ---------------------------------------------------------------------------
__global__ __launch_bounds__(256) void k_hist(const int* __restrict__ ei,
                                              int* __restrict__ deg) {
    int e = blockIdx.x * 256 + threadIdx.x;
    if (e < NE) atomicAdd(&deg[ei[NE + e]], 1);
}

__global__ __launch_bounds__(256) void k_scan1(const int* __restrict__ deg,
                                               int* __restrict__ excl,
                                               int* __restrict__ bsum) {
    __shared__ int s[256];
    int i = blockIdx.x * 256 + threadIdx.x;
    int v = (i < NN) ? deg[i] : 0;
    s[threadIdx.x] = v;
    __syncthreads();
    #pragma unroll
    for (int st = 1; st < 256; st <<= 1) {
        int t = (threadIdx.x >= st) ? s[threadIdx.x - st] : 0;
        __syncthreads();
        s[threadIdx.x] += t;
        __syncthreads();
    }
    if (i < NN) excl[i] = s[threadIdx.x] - v;
    if (threadIdx.x == 255) bsum[blockIdx.x] = s[255];
}

__global__ __launch_bounds__(512) void k_scan2(int* __restrict__ bsum, int nb) {
    __shared__ int s[512];
    int v = (threadIdx.x < nb) ? bsum[threadIdx.x] : 0;
    s[threadIdx.x] = v;
    __syncthreads();
    #pragma unroll
    for (int st = 1; st < 512; st <<= 1) {
        int t = (threadIdx.x >= st) ? s[threadIdx.x - st] : 0;
        __syncthreads();
        s[threadIdx.x] += t;
        __syncthreads();
    }
    if (threadIdx.x < nb) bsum[threadIdx.x] = s[threadIdx.x] - v;  // exclusive
}

__global__ __launch_bounds__(256) void k_scan3(const int* __restrict__ excl,
                                               const int* __restrict__ bsum,
                                               int* __restrict__ off,
                                               int* __restrict__ cur) {
    int i = blockIdx.x * 256 + threadIdx.x;
    if (i < NN) {
        int o = excl[i] + bsum[blockIdx.x];
        off[i] = o;
        cur[i] = o;
    }
    if (i == 0) off[NN] = NE;
}

__global__ __launch_bounds__(256) void k_fill(const int* __restrict__ ei,
                                              int* __restrict__ cur,
                                              int* __restrict__ srcs) {
    int e = blockIdx.x * 256 + threadIdx.x;
    if (e < NE) {
        int d = ei[NE + e];
        int p = atomicAdd(&cur[d], 1);
        srcs[p] = ei[e];
    }
}

// ---------------------------------------------------------------------------
// Graph offsets from sorted batch via boundary scan, plus biasF init.
// ---------------------------------------------------------------------------
__global__ __launch_bounds__(256) void k_goff(const int* __restrict__ batch,
                                              int* __restrict__ goff,
                                              const float* __restrict__ b2all,
                                              float* __restrict__ biasFall) {
    int i = blockIdx.x * 256 + threadIdx.x;
    if (blockIdx.x == 0) {
        for (int j = threadIdx.x; j < NL * D; j += 256) biasFall[j] = b2all[j];
    }
    if (i == 0) {
        int b0 = batch[0];
        for (int g = 0; g <= b0; ++g) goff[g] = 0;
    }
    if (i < NN - 1) {
        int b = batch[i], bn = batch[i + 1];
        for (int g = b + 1; g <= bn; ++g) goff[g] = i + 1;
    }
    if (i == NN - 1) {
        int b = batch[NN - 1];
        for (int g = b + 1; g <= NG; ++g) goff[g] = NN;
    }
}

// ---------------------------------------------------------------------------
// Gather aggregation (layer 0): G[n] = x[n] + sum_{s in N_in(n)} x[s]
// ---------------------------------------------------------------------------
__global__ __launch_bounds__(256) void k_gather(const float4* __restrict__ hin,
                                                const int* __restrict__ off,
                                                const int* __restrict__ srcs,
                                                float4* __restrict__ g) {
    int t = blockIdx.x * 256 + threadIdx.x;
    int n = t >> 5;
    if (n >= NN) return;
    int f4 = t & 31;
    int lo = off[n], hi = off[n + 1];
    float4 acc = hin[(long)n * 32 + f4];
    for (int e = lo; e < hi; ++e) {
        int s = srcs[e];
        float4 v = hin[(long)s * 32 + f4];
        acc.x += v.x; acc.y += v.y; acc.z += v.z; acc.w += v.w;
    }
    g[(long)n * 32 + f4] = acc;
}

// Gather with fused affine+ReLU (layers 1,2): h = relu(y2*A+B) on the fly.
__global__ __launch_bounds__(256) void k_gather_aff(const float4* __restrict__ yin,
                                                    const int* __restrict__ off,
                                                    const int* __restrict__ srcs,
                                                    const float* __restrict__ affA,
                                                    const float* __restrict__ affB,
                                                    float4* __restrict__ g) {
    int t = blockIdx.x * 256 + threadIdx.x;
    int n = t >> 5;
    if (n >= NN) return;
    int f4 = t & 31;
    float4 A = *(const float4*)(affA + f4 * 4);
    float4 B = *(const float4*)(affB + f4 * 4);
    int lo = off[n], hi = off[n + 1];
    float4 v = yin[(long)n * 32 + f4];
    float4 acc;
    acc.x = fmaxf(fmaf(v.x, A.x, B.x), 0.f);
    acc.y = fmaxf(fmaf(v.y, A.y, B.y), 0.f);
    acc.z = fmaxf(fmaf(v.z, A.z, B.z), 0.f);
    acc.w = fmaxf(fmaf(v.w, A.w, B.w), 0.f);
    for (int e = lo; e < hi; ++e) {
        int s = srcs[e];
        float4 u = yin[(long)s * 32 + f4];
        acc.x += fmaxf(fmaf(u.x, A.x, B.x), 0.f);
        acc.y += fmaxf(fmaf(u.y, A.y, B.y), 0.f);
        acc.z += fmaxf(fmaf(u.z, A.z, B.z), 0.f);
        acc.w += fmaxf(fmaf(u.w, A.w, B.w), 0.f);
    }
    g[(long)n * 32 + f4] = acc;
}

// ---------------------------------------------------------------------------
// fp32 GEMM + fused column stats. 128 threads, BM=64 (grid 1563), BK=32,
// 8x8 micro-tile: 64 FMA per 4 ds_read_b128 (2x the FMA:LDS-latency ratio of
// the 4x8 version whose VALUBusy pinned at 31%). Global->reg->LDS chunk
// prefetch hides HBM/L2 latency under the previous chunk's FMA phase.
// LDS 24.6 KB -> 6 blocks/CU = 12 waves/CU (LDS-bound; VGPR can't bind below
// 682 at 3 waves/SIMD). Stats LDS-reduced, 2 atomics/col/block.
// ---------------------------------------------------------------------------
#define BM 64
#define BK 32
#define RST 65

__global__ __launch_bounds__(128, 3) void k_gemm(const float* __restrict__ A,
                                                 const float* __restrict__ W,
                                                 const float* __restrict__ bias,
                                                 float* __restrict__ C,
                                                 float* __restrict__ sum,
                                                 float* __restrict__ sq) {
    __shared__ float Ws[BK * 128];   // 16 KB; reused as stats scratch
    __shared__ float As[BK * RST];   // 8.3 KB
    const int tid = threadIdx.x;     // 0..127
    const int ty = tid >> 4;         // 0..7  -> rows ty*8..+7
    const int tx = tid & 15;         // 0..15 -> cols tx*8..+7
    const long base = (long)blockIdx.x * BM;

    float4 wpre[8];   // W chunk: 1024 quads / 128 threads
    float4 apre[4];   // A chunk: 512 quads / 128 threads

    // prologue: prefetch chunk 0
    #pragma unroll
    for (int j = 0; j < 8; ++j) {
        int e = tid + j * 128;
        int k = e >> 5, q = e & 31;
        wpre[j] = *(const float4*)(W + (long)k * 128 + q * 4);
    }
    #pragma unroll
    for (int j = 0; j < 4; ++j) {
        int e = tid + j * 128;
        int row = e >> 3, cq = e & 7;
        long gr = base + row;
        apre[j] = (gr < NN) ? *(const float4*)(A + gr * D + cq * 4)
                            : make_float4(0.f, 0.f, 0.f, 0.f);
    }

    float acc[8][8];
    #pragma unroll
    for (int i = 0; i < 8; ++i)
        #pragma unroll
        for (int c = 0; c < 8; ++c) acc[i][c] = 0.f;

    for (int c = 0; c < 4; ++c) {
        // write staged regs to LDS (W quad-permuted p(q) = (q&1)*16 + q>>1)
        #pragma unroll
        for (int j = 0; j < 8; ++j) {
            int e = tid + j * 128;
            int k = e >> 5, q = e & 31;
            int p = ((q & 1) << 4) + (q >> 1);
            *(float4*)(&Ws[k * 128 + p * 4]) = wpre[j];
        }
        #pragma unroll
        for (int j = 0; j < 4; ++j) {
            int e = tid + j * 128;
            int row = e >> 3, cq = e & 7;
            As[(cq * 4 + 0) * RST + row] = apre[j].x;
            As[(cq * 4 + 1) * RST + row] = apre[j].y;
            As[(cq * 4 + 2) * RST + row] = apre[j].z;
            As[(cq * 4 + 3) * RST + row] = apre[j].w;
        }
        __syncthreads();
        // issue next chunk's global loads; they retire under this chunk's FMAs
        if (c < 3) {
            int kc = (c + 1) * BK;
            #pragma unroll
            for (int j = 0; j < 8; ++j) {
                int e = tid + j * 128;
                int k = e >> 5, q = e & 31;
                wpre[j] = *(const float4*)(W + (long)(kc + k) * 128 + q * 4);
            }
            #pragma unroll
            for (int j = 0; j < 4; ++j) {
                int e = tid + j * 128;
                int row = e >> 3, cq = e & 7;
                long gr = base + row;
                apre[j] = (gr < NN) ? *(const float4*)(A + gr * D + kc + cq * 4)
                                    : make_float4(0.f, 0.f, 0.f, 0.f);
            }
        }
        #pragma unroll
        for (int k = 0; k < BK; ++k) {
            float4 a0 = *(const float4*)(&As[k * RST + ty * 8]);
            float4 a1 = *(const float4*)(&As[k * RST + ty * 8 + 4]);
            float4 w0 = *(const float4*)(&Ws[k * 128 + tx * 4]);
            float4 w1 = *(const float4*)(&Ws[k * 128 + 64 + tx * 4]);
            float av[8] = {a0.x, a0.y, a0.z, a0.w, a1.x, a1.y, a1.z, a1.w};
            float wv[8] = {w0.x, w0.y, w0.z, w0.w, w1.x, w1.y, w1.z, w1.w};
            #pragma unroll
            for (int i = 0; i < 8; ++i)
                #pragma unroll
                for (int cc = 0; cc < 8; ++cc)
                    acc[i][cc] = fmaf(av[i], wv[cc], acc[i][cc]);
        }
        __syncthreads();
    }

    float4 b0 = *(const float4*)(bias + tx * 8);
    float4 b1 = *(const float4*)(bias + tx * 8 + 4);
    float bv[8] = {b0.x, b0.y, b0.z, b0.w, b1.x, b1.y, b1.z, b1.w};
    float csum[8], csq[8];
    #pragma unroll
    for (int c = 0; c < 8; ++c) { csum[c] = 0.f; csq[c] = 0.f; }
    #pragma unroll
    for (int i = 0; i < 8; ++i) {
        long gr = base + ty * 8 + i;
        if (gr < NN) {
            float o[8];
            #pragma unroll
            for (int c = 0; c < 8; ++c) {
                o[c] = acc[i][c] + bv[c];
                csum[c] += o[c];
                csq[c] += o[c] * o[c];
            }
            *(float4*)(C + gr * D + tx * 8) = make_float4(o[0], o[1], o[2], o[3]);
            *(float4*)(C + gr * D + tx * 8 + 4) = make_float4(o[4], o[5], o[6], o[7]);
        }
    }
    // stats reduction in LDS (reuse Ws: [8][128] sum + [8][128] sq)
    float* red = Ws;
    *(float4*)(&red[ty * 128 + tx * 8]) = make_float4(csum[0], csum[1], csum[2], csum[3]);
    *(float4*)(&red[ty * 128 + tx * 8 + 4]) = make_float4(csum[4], csum[5], csum[6], csum[7]);
    *(float4*)(&red[1024 + ty * 128 + tx * 8]) = make_float4(csq[0], csq[1], csq[2], csq[3]);
    *(float4*)(&red[1024 + ty * 128 + tx * 8 + 4]) = make_float4(csq[4], csq[5], csq[6], csq[7]);
    __syncthreads();
    float tsum = 0.f, tsq = 0.f;
    #pragma unroll
    for (int j = 0; j < 8; ++j) {
        tsum += red[j * 128 + tid];
        tsq  += red[1024 + j * 128 + tid];
    }
    atomicAdd(sum + tid, tsum);
    atomicAdd(sq + tid, tsq);
}

// ---------------------------------------------------------------------------
// Fused BN1-finalize + fold into GEMM2 operands (biasF pre-initialized to b2).
// Block k consumes sum[k]/sq[k] then zeroes them for the next GEMM.
// ---------------------------------------------------------------------------
__global__ __launch_bounds__(128) void k_fold(const float* __restrict__ W2,
                                              float* __restrict__ sum,
                                              float* __restrict__ sq,
                                              const float* __restrict__ g1,
                                              const float* __restrict__ bt1,
                                              float* __restrict__ W2s,
                                              float* __restrict__ biasF) {
    int k = blockIdx.x, j = threadIdx.x;
    float m = sum[k] * (1.f / NN);
    float v = sq[k] * (1.f / NN) - m * m;
    __syncthreads();
    if (j == 0) { sum[k] = 0.f; sq[k] = 0.f; }
    float a = g1[k] * rsqrtf(v + EPS);
    float c = bt1[k] - m * a;
    float w = W2[(long)k * 128 + j];
    W2s[(long)k * 128 + j] = a * w;
    atomicAdd(biasF + j, c * w);
}

// BN2 + outer BN collapse: A = rs2*g2*rso*go, B = bo - m2*A. Zeroes sum/sq.
__global__ void k_fin2(float* __restrict__ sum, float* __restrict__ sq,
                       const float* __restrict__ g2, const float* __restrict__ go,
                       const float* __restrict__ bo, float* __restrict__ affA,
                       float* __restrict__ affB) {
    int f = threadIdx.x;
    float m = sum[f] * (1.f / NN);
    float v = sq[f] * (1.f / NN) - m * m;
    sum[f] = 0.f;
    sq[f] = 0.f;
    float t = g2[f] * rsqrtf(v + EPS);
    float vo = t * t * v;
    float Aa = t * rsqrtf(vo + EPS) * go[f];
    affA[f] = Aa;
    affB[f] = bo[f] - m * Aa;
}

// ---------------------------------------------------------------------------
// Final-layer affine+ReLU fused with per-graph sum accumulation.
// ---------------------------------------------------------------------------
__global__ __launch_bounds__(256) void k_affine_pool(const float4* __restrict__ Y,
                                                     const float* __restrict__ affA,
                                                     const float* __restrict__ affB,
                                                     const int* __restrict__ batch,
                                                     float4* __restrict__ nodeEmb,
                                                     float* __restrict__ gsum) {
    int tid = threadIdx.x;
    int f4 = tid & 31;
    int rg = tid >> 5;
    long base = (long)blockIdx.x * 64 + (long)rg * 8;
    float4 A = *(const float4*)(affA + f4 * 4);
    float4 B = *(const float4*)(affB + f4 * 4);
    float4 run = make_float4(0.f, 0.f, 0.f, 0.f);
    int curg = -1;
    #pragma unroll
    for (int i = 0; i < 8; ++i) {
        long r = base + i;
        if (r >= NN) break;
        int g = batch[r];
        float4 v = Y[r * 32 + f4];
        float4 o;
        o.x = fmaxf(fmaf(v.x, A.x, B.x), 0.f);
        o.y = fmaxf(fmaf(v.y, A.y, B.y), 0.f);
        o.z = fmaxf(fmaf(v.z, A.z, B.z), 0.f);
        o.w = fmaxf(fmaf(v.w, A.w, B.w), 0.f);
        nodeEmb[r * 32 + f4] = o;
        if (g != curg) {
            if (curg >= 0) {
                float* p = gsum + (long)curg * D + f4 * 4;
                atomicAdd(p + 0, run.x); atomicAdd(p + 1, run.y);
                atomicAdd(p + 2, run.z); atomicAdd(p + 3, run.w);
            }
            curg = g;
            run = o;
        } else {
            run.x += o.x; run.y += o.y; run.z += o.z; run.w += o.w;
        }
    }
    if (curg >= 0) {
        float* p = gsum + (long)curg * D + f4 * 4;
        atomicAdd(p + 0, run.x); atomicAdd(p + 1, run.y);
        atomicAdd(p + 2, run.z); atomicAdd(p + 3, run.w);
    }
}

// Finalize: mean from gsum/goff, write ge, fc(128->2) reduce -> out.
__global__ __launch_bounds__(128) void k_fc(const float* __restrict__ gsum,
                                            const int* __restrict__ goff,
                                            const float* __restrict__ fcW,
                                            const float* __restrict__ fcb,
                                            float* __restrict__ ge,
                                            float* __restrict__ out) {
    __shared__ float r0[128], r1[128];
    int g = blockIdx.x, j = threadIdx.x;
    int cnt = goff[g + 1] - goff[g];
    float mean = gsum[(long)g * D + j] / (float)(cnt > 0 ? cnt : 1);
    ge[(long)g * D + j] = mean;
    r0[j] = mean * fcW[j * 2 + 0];
    r1[j] = mean * fcW[j * 2 + 1];
    __syncthreads();
    for (int st = 64; st > 0; st >>= 1) {
        if (j < st) { r0[j] += r0[j + st]; r1[j] += r1[j + st]; }
        __syncthreads();
    }
    if (j == 0) {
        out[g * 2 + 0] = r0[0] + fcb[0];
        out[g * 2 + 1] = r1[0] + fcb[1];
    }
}

// ---------------------------------------------------------------------------
extern "C" void kernel_launch(void* const* d_in, const int* in_sizes, int n_in,
                              void* d_out, int out_size, void* d_ws, size_t ws_size,
                              hipStream_t stream) {
    const float* x   = (const float*)d_in[0];
    const int*   ei  = (const int*)d_in[1];
    const int*   bat = (const int*)d_in[2];
    const float* W1  = (const float*)d_in[3];
    const float* b1  = (const float*)d_in[4];
    const float* g1  = (const float*)d_in[5];
    const float* bt1 = (const float*)d_in[6];
    const float* W2  = (const float*)d_in[7];
    const float* b2  = (const float*)d_in[8];
    const float* g2  = (const float*)d_in[9];
    const float* go  = (const float*)d_in[11];
    const float* bo  = (const float*)d_in[12];
    const float* fcW = (const float*)d_in[13];
    const float* fcb = (const float*)d_in[14];

    const long ND = (long)NN * D;
    float* H = (float*)d_ws;
    float* G = H + ND;
    float* S = G + ND;
    float* sum      = S;                       // 128
    float* sq       = S + 128;                 // 128
    float* gsum     = S + 256;                 // NG*D = 65536
    float* biasFall = S + 65792;               // NL*D = 384
    float* affA     = S + 66176;               // 128
    float* affB     = S + 66304;               // 128
    float* W2s      = S + 66432;               // 16384
    int*   goff     = (int*)(S + 82816);       // NG+1
    int*   off      = (int*)(S + 83840);       // NN+1
    int*   srcs     = off + (NN + 1);          // NE

    float* nodeEmb = (float*)d_out;     // also GEMM1 scratch Y
    float* ge   = nodeEmb + ND;
    float* out2 = ge + (long)NG * D;
    float* Y = nodeEmb;

    // CSR-build temporaries alias into nodeEmb (consumed before first GEMM)
    int* deg  = (int*)nodeEmb;
    int* excl = deg + NN;
    int* cur  = excl + NN;
    int* bsum = cur + NN;

    const int edgeGrid = (NE + 255) / 256;
    const int nodeGrid = (NN + 255) / 256;
    const int gathGrid = (int)(((long)NN * 32 + 255) / 256);
    const int gemmGrid = (NN + BM - 1) / BM;     // 1563
    const int apGrid   = (NN + 63) / 64;         // 1563

    hipMemsetAsync(deg, 0, NN * sizeof(int), stream);
    k_hist<<<edgeGrid, 256, 0, stream>>>(ei, deg);
    k_scan1<<<nodeGrid, 256, 0, stream>>>(deg, excl, bsum);
    k_scan2<<<1, 512, 0, stream>>>(bsum, nodeGrid);
    k_scan3<<<nodeGrid, 256, 0, stream>>>(excl, bsum, off, cur);
    k_fill<<<edgeGrid, 256, 0, stream>>>(ei, cur, srcs);

    // zero sum/sq/gsum in one shot; k_fold/k_fin2 re-zero sum/sq per GEMM
    hipMemsetAsync(sum, 0, (256 + (long)NG * D) * sizeof(float), stream);
    k_goff<<<nodeGrid, 256, 0, stream>>>(bat, goff, b2, biasFall);

    for (int l = 0; l < NL; ++l) {
        if (l == 0)
            k_gather<<<gathGrid, 256, 0, stream>>>((const float4*)x, off, srcs,
                                                   (float4*)G);
        else
            k_gather_aff<<<gathGrid, 256, 0, stream>>>((const float4*)G, off, srcs,
                                                       affA, affB, (float4*)H);
        const float* gin = (l == 0) ? G : H;

        k_gemm<<<gemmGrid, 128, 0, stream>>>(gin, W1 + (long)l * D * D, b1 + l * D,
                                             Y, sum, sq);
        k_fold<<<128, 128, 0, stream>>>(W2 + (long)l * D * D, sum, sq,
                                        g1 + l * D, bt1 + l * D, W2s,
                                        biasFall + (long)l * D);

        k_gemm<<<gemmGrid, 128, 0, stream>>>(Y, W2s, biasFall + (long)l * D,
                                             G, sum, sq);
        k_fin2<<<1, 128, 0, stream>>>(sum, sq, g2 + l * D, go + l * D, bo + l * D,
                                      affA, affB);
    }

    k_affine_pool<<<apGrid, 256, 0, stream>>>((const float4*)G, affA, affB, bat,
                                              (float4*)nodeEmb, gsum);
    k_fc<<<NG, 128, 0, stream>>>(gsum, goff, fcW, fcb, ge, out2);
}

// Round 10
// 1013.535 us; speedup vs baseline: 1.2079x; 1.2079x over previous
//
#include <hip/hip_runtime.h>

#define NN 100000
#define NE 600000
#define NG 512
#define D 128
#define NL 3
#define EPS 1e-5f

// ---------------------------------------------------------------------------
// CSR build: histogram -> exclusive scan -> fill (sorted-by-dst source list)
// ---------------------------------------------------------------------------
__global__ __launch_bounds__(256) void k_hist(const int* __restrict__ ei,
                                              int* __restrict__ deg) {
    int e = blockIdx.x * 256 + threadIdx.x;
    if (e < NE) atomicAdd(&deg[ei[NE + e]], 1);
}

__global__ __launch_bounds__(256) void k_scan1(const int* __restrict__ deg,
                                               int* __restrict__ excl,
                                               int* __restrict__ bsum) {
    __shared__ int s[256];
    int i = blockIdx.x * 256 + threadIdx.x;
    int v = (i < NN) ? deg[i] : 0;
    s[threadIdx.x] = v;
    __syncthreads();
    #pragma unroll
    for (int st = 1; st < 256; st <<= 1) {
        int t = (threadIdx.x >= st) ? s[threadIdx.x - st] : 0;
        __syncthreads();
        s[threadIdx.x] += t;
        __syncthreads();
    }
    if (i < NN) excl[i] = s[threadIdx.x] - v;
    if (threadIdx.x == 255) bsum[blockIdx.x] = s[255];
}

__global__ __launch_bounds__(512) void k_scan2(int* __restrict__ bsum, int nb) {
    __shared__ int s[512];
    int v = (threadIdx.x < nb) ? bsum[threadIdx.x] : 0;
    s[threadIdx.x] = v;
    __syncthreads();
    #pragma unroll
    for (int st = 1; st < 512; st <<= 1) {
        int t = (threadIdx.x >= st) ? s[threadIdx.x - st] : 0;
        __syncthreads();
        s[threadIdx.x] += t;
        __syncthreads();
    }
    if (threadIdx.x < nb) bsum[threadIdx.x] = s[threadIdx.x] - v;  // exclusive
}

__global__ __launch_bounds__(256) void k_scan3(const int* __restrict__ excl,
                                               const int* __restrict__ bsum,
                                               int* __restrict__ off,
                                               int* __restrict__ cur) {
    int i = blockIdx.x * 256 + threadIdx.x;
    if (i < NN) {
        int o = excl[i] + bsum[blockIdx.x];
        off[i] = o;
        cur[i] = o;
    }
    if (i == 0) off[NN] = NE;
}

__global__ __launch_bounds__(256) void k_fill(const int* __restrict__ ei,
                                              int* __restrict__ cur,
                                              int* __restrict__ srcs) {
    int e = blockIdx.x * 256 + threadIdx.x;
    if (e < NE) {
        int d = ei[NE + e];
        int p = atomicAdd(&cur[d], 1);
        srcs[p] = ei[e];
    }
}

// ---------------------------------------------------------------------------
// Graph offsets from sorted batch via boundary scan, plus biasF init.
// ---------------------------------------------------------------------------
__global__ __launch_bounds__(256) void k_goff(const int* __restrict__ batch,
                                              int* __restrict__ goff,
                                              const float* __restrict__ b2all,
                                              float* __restrict__ biasFall) {
    int i = blockIdx.x * 256 + threadIdx.x;
    if (blockIdx.x == 0) {
        for (int j = threadIdx.x; j < NL * D; j += 256) biasFall[j] = b2all[j];
    }
    if (i == 0) {
        int b0 = batch[0];
        for (int g = 0; g <= b0; ++g) goff[g] = 0;
    }
    if (i < NN - 1) {
        int b = batch[i], bn = batch[i + 1];
        for (int g = b + 1; g <= bn; ++g) goff[g] = i + 1;
    }
    if (i == NN - 1) {
        int b = batch[NN - 1];
        for (int g = b + 1; g <= NG; ++g) goff[g] = NN;
    }
}

// ---------------------------------------------------------------------------
// Gather aggregation (layer 0): G[n] = x[n] + sum_{s in N_in(n)} x[s]
// ---------------------------------------------------------------------------
__global__ __launch_bounds__(256) void k_gather(const float4* __restrict__ hin,
                                                const int* __restrict__ off,
                                                const int* __restrict__ srcs,
                                                float4* __restrict__ g) {
    int t = blockIdx.x * 256 + threadIdx.x;
    int n = t >> 5;
    if (n >= NN) return;
    int f4 = t & 31;
    int lo = off[n], hi = off[n + 1];
    float4 acc = hin[(long)n * 32 + f4];
    for (int e = lo; e < hi; ++e) {
        int s = srcs[e];
        float4 v = hin[(long)s * 32 + f4];
        acc.x += v.x; acc.y += v.y; acc.z += v.z; acc.w += v.w;
    }
    g[(long)n * 32 + f4] = acc;
}

// Gather with fused affine+ReLU (layers 1,2): h = relu(y2*A+B) on the fly.
__global__ __launch_bounds__(256) void k_gather_aff(const float4* __restrict__ yin,
                                                    const int* __restrict__ off,
                                                    const int* __restrict__ srcs,
                                                    const float* __restrict__ affA,
                                                    const float* __restrict__ affB,
                                                    float4* __restrict__ g) {
    int t = blockIdx.x * 256 + threadIdx.x;
    int n = t >> 5;
    if (n >= NN) return;
    int f4 = t & 31;
    float4 A = *(const float4*)(affA + f4 * 4);
    float4 B = *(const float4*)(affB + f4 * 4);
    int lo = off[n], hi = off[n + 1];
    float4 v = yin[(long)n * 32 + f4];
    float4 acc;
    acc.x = fmaxf(fmaf(v.x, A.x, B.x), 0.f);
    acc.y = fmaxf(fmaf(v.y, A.y, B.y), 0.f);
    acc.z = fmaxf(fmaf(v.z, A.z, B.z), 0.f);
    acc.w = fmaxf(fmaf(v.w, A.w, B.w), 0.f);
    for (int e = lo; e < hi; ++e) {
        int s = srcs[e];
        float4 u = yin[(long)s * 32 + f4];
        acc.x += fmaxf(fmaf(u.x, A.x, B.x), 0.f);
        acc.y += fmaxf(fmaf(u.y, A.y, B.y), 0.f);
        acc.z += fmaxf(fmaf(u.z, A.z, B.z), 0.f);
        acc.w += fmaxf(fmaf(u.w, A.w, B.w), 0.f);
    }
    g[(long)n * 32 + f4] = acc;
}

// ---------------------------------------------------------------------------
// fp32 GEMM + fused column stats. 256 threads, BM=128 (grid 782), BK=32,
// 8x8 micro-tile as two 4-row groups (rows ty*4+i and 64+ty*4+i) so all four
// ds_read_b128 fragment reads are 2-way bank-aliased (free). 4 LDS reads per
// 64 FMAs halves the LDS-pipe:FMA ratio vs the 4x8 version (which was
// LDS-issue-bound at ~80us). Global->reg->LDS prefetch hides vmcnt under FMA.
// Plain launch_bounds(256): NO min-waves cap -> no spill (R7 lesson: the cap
// forced VGPR=84 and spilled acc to scratch, 279MB WRITE_SIZE).
// LDS 32.6 KB; expected ~140 VGPR -> 3 waves/SIMD = 3 blocks/CU, grid offers 3.05.
// ---------------------------------------------------------------------------
#define BM 128
#define BK 32
#define RST 129

__global__ __launch_bounds__(256) void k_gemm(const float* __restrict__ A,
                                              const float* __restrict__ W,
                                              const float* __restrict__ bias,
                                              float* __restrict__ C,
                                              float* __restrict__ sum,
                                              float* __restrict__ sq) {
    __shared__ float Ws[BK * 128];   // 16 KB; reused as stats scratch (4096 f)
    __shared__ float As[BK * RST];   // 16.5 KB
    const int tid = threadIdx.x;     // 0..255
    const int ty = tid >> 4;         // 0..15 -> rows ty*4..+3 and 64+ty*4..+3
    const int tx = tid & 15;         // 0..15 -> cols tx*8..+7
    const long base = (long)blockIdx.x * BM;

    float4 wpre[4];   // W chunk: 1024 quads / 256 threads
    float4 apre[4];   // A chunk: 1024 quads / 256 threads

    // prologue: prefetch chunk 0
    #pragma unroll
    for (int j = 0; j < 4; ++j) {
        int e = tid + j * 256;
        int k = e >> 5, q = e & 31;
        wpre[j] = *(const float4*)(W + (long)k * 128 + q * 4);
    }
    #pragma unroll
    for (int j = 0; j < 4; ++j) {
        int e = tid + j * 256;
        int row = e >> 3, cq = e & 7;
        long gr = base + row;
        apre[j] = (gr < NN) ? *(const float4*)(A + gr * D + cq * 4)
                            : make_float4(0.f, 0.f, 0.f, 0.f);
    }

    float acc[8][8];
    #pragma unroll
    for (int i = 0; i < 8; ++i)
        #pragma unroll
        for (int c = 0; c < 8; ++c) acc[i][c] = 0.f;

    for (int c = 0; c < 4; ++c) {
        // write staged regs to LDS (W quad-permuted p(q) = (q&1)*16 + q>>1)
        #pragma unroll
        for (int j = 0; j < 4; ++j) {
            int e = tid + j * 256;
            int k = e >> 5, q = e & 31;
            int p = ((q & 1) << 4) + (q >> 1);
            *(float4*)(&Ws[k * 128 + p * 4]) = wpre[j];
        }
        #pragma unroll
        for (int j = 0; j < 4; ++j) {
            int e = tid + j * 256;
            int row = e >> 3, cq = e & 7;
            As[(cq * 4 + 0) * RST + row] = apre[j].x;
            As[(cq * 4 + 1) * RST + row] = apre[j].y;
            As[(cq * 4 + 2) * RST + row] = apre[j].z;
            As[(cq * 4 + 3) * RST + row] = apre[j].w;
        }
        __syncthreads();
        // issue next chunk's global loads; they retire under this chunk's FMAs
        if (c < 3) {
            int kc = (c + 1) * BK;
            #pragma unroll
            for (int j = 0; j < 4; ++j) {
                int e = tid + j * 256;
                int k = e >> 5, q = e & 31;
                wpre[j] = *(const float4*)(W + (long)(kc + k) * 128 + q * 4);
            }
            #pragma unroll
            for (int j = 0; j < 4; ++j) {
                int e = tid + j * 256;
                int row = e >> 3, cq = e & 7;
                long gr = base + row;
                apre[j] = (gr < NN) ? *(const float4*)(A + gr * D + kc + cq * 4)
                                    : make_float4(0.f, 0.f, 0.f, 0.f);
            }
        }
        #pragma unroll
        for (int k = 0; k < BK; ++k) {
            float4 a0 = *(const float4*)(&As[k * RST + ty * 4]);        // rows ty*4..+3
            float4 a1 = *(const float4*)(&As[k * RST + 64 + ty * 4]);   // rows 64+ty*4..+3
            float4 w0 = *(const float4*)(&Ws[k * 128 + tx * 4]);        // cols tx*8..+3
            float4 w1 = *(const float4*)(&Ws[k * 128 + 64 + tx * 4]);   // cols tx*8+4..+7
            float av[8] = {a0.x, a0.y, a0.z, a0.w, a1.x, a1.y, a1.z, a1.w};
            float wv[8] = {w0.x, w0.y, w0.z, w0.w, w1.x, w1.y, w1.z, w1.w};
            #pragma unroll
            for (int i = 0; i < 8; ++i)
                #pragma unroll
                for (int cc = 0; cc < 8; ++cc)
                    acc[i][cc] = fmaf(av[i], wv[cc], acc[i][cc]);
        }
        __syncthreads();
    }

    float4 b0 = *(const float4*)(bias + tx * 8);
    float4 b1 = *(const float4*)(bias + tx * 8 + 4);
    float bv[8] = {b0.x, b0.y, b0.z, b0.w, b1.x, b1.y, b1.z, b1.w};
    float csum[8], csq[8];
    #pragma unroll
    for (int c = 0; c < 8; ++c) { csum[c] = 0.f; csq[c] = 0.f; }
    #pragma unroll
    for (int i = 0; i < 8; ++i) {
        int row = (i < 4) ? (ty * 4 + i) : (64 + ty * 4 + (i - 4));
        long gr = base + row;
        if (gr < NN) {
            float o[8];
            #pragma unroll
            for (int c = 0; c < 8; ++c) {
                o[c] = acc[i][c] + bv[c];
                csum[c] += o[c];
                csq[c] += o[c] * o[c];
            }
            *(float4*)(C + gr * D + tx * 8) = make_float4(o[0], o[1], o[2], o[3]);
            *(float4*)(C + gr * D + tx * 8 + 4) = make_float4(o[4], o[5], o[6], o[7]);
        }
    }
    // stats reduction in LDS (reuse Ws: [16][128] sum + [16][128] sq)
    float* red = Ws;
    *(float4*)(&red[ty * 128 + tx * 8]) = make_float4(csum[0], csum[1], csum[2], csum[3]);
    *(float4*)(&red[ty * 128 + tx * 8 + 4]) = make_float4(csum[4], csum[5], csum[6], csum[7]);
    *(float4*)(&red[2048 + ty * 128 + tx * 8]) = make_float4(csq[0], csq[1], csq[2], csq[3]);
    *(float4*)(&red[2048 + ty * 128 + tx * 8 + 4]) = make_float4(csq[4], csq[5], csq[6], csq[7]);
    __syncthreads();
    if (tid < 128) {
        float t = 0.f;
        #pragma unroll
        for (int j = 0; j < 16; ++j) t += red[j * 128 + tid];
        atomicAdd(sum + tid, t);
    } else {
        int col = tid - 128;
        float t = 0.f;
        #pragma unroll
        for (int j = 0; j < 16; ++j) t += red[2048 + j * 128 + col];
        atomicAdd(sq + col, t);
    }
}

// ---------------------------------------------------------------------------
// Fused BN1-finalize + fold into GEMM2 operands (biasF pre-initialized to b2).
// Block k consumes sum[k]/sq[k] then zeroes them for the next GEMM.
// ---------------------------------------------------------------------------
__global__ __launch_bounds__(128) void k_fold(const float* __restrict__ W2,
                                              float* __restrict__ sum,
                                              float* __restrict__ sq,
                                              const float* __restrict__ g1,
                                              const float* __restrict__ bt1,
                                              float* __restrict__ W2s,
                                              float* __restrict__ biasF) {
    int k = blockIdx.x, j = threadIdx.x;
    float m = sum[k] * (1.f / NN);
    float v = sq[k] * (1.f / NN) - m * m;
    __syncthreads();
    if (j == 0) { sum[k] = 0.f; sq[k] = 0.f; }
    float a = g1[k] * rsqrtf(v + EPS);
    float c = bt1[k] - m * a;
    float w = W2[(long)k * 128 + j];
    W2s[(long)k * 128 + j] = a * w;
    atomicAdd(biasF + j, c * w);
}

// BN2 + outer BN collapse: A = rs2*g2*rso*go, B = bo - m2*A. Zeroes sum/sq.
__global__ void k_fin2(float* __restrict__ sum, float* __restrict__ sq,
                       const float* __restrict__ g2, const float* __restrict__ go,
                       const float* __restrict__ bo, float* __restrict__ affA,
                       float* __restrict__ affB) {
    int f = threadIdx.x;
    float m = sum[f] * (1.f / NN);
    float v = sq[f] * (1.f / NN) - m * m;
    sum[f] = 0.f;
    sq[f] = 0.f;
    float t = g2[f] * rsqrtf(v + EPS);
    float vo = t * t * v;
    float Aa = t * rsqrtf(vo + EPS) * go[f];
    affA[f] = Aa;
    affB[f] = bo[f] - m * Aa;
}

// ---------------------------------------------------------------------------
// Final-layer affine+ReLU fused with per-graph sum accumulation.
// ---------------------------------------------------------------------------
__global__ __launch_bounds__(256) void k_affine_pool(const float4* __restrict__ Y,
                                                     const float* __restrict__ affA,
                                                     const float* __restrict__ affB,
                                                     const int* __restrict__ batch,
                                                     float4* __restrict__ nodeEmb,
                                                     float* __restrict__ gsum) {
    int tid = threadIdx.x;
    int f4 = tid & 31;
    int rg = tid >> 5;
    long base = (long)blockIdx.x * 64 + (long)rg * 8;
    float4 A = *(const float4*)(affA + f4 * 4);
    float4 B = *(const float4*)(affB + f4 * 4);
    float4 run = make_float4(0.f, 0.f, 0.f, 0.f);
    int curg = -1;
    #pragma unroll
    for (int i = 0; i < 8; ++i) {
        long r = base + i;
        if (r >= NN) break;
        int g = batch[r];
        float4 v = Y[r * 32 + f4];
        float4 o;
        o.x = fmaxf(fmaf(v.x, A.x, B.x), 0.f);
        o.y = fmaxf(fmaf(v.y, A.y, B.y), 0.f);
        o.z = fmaxf(fmaf(v.z, A.z, B.z), 0.f);
        o.w = fmaxf(fmaf(v.w, A.w, B.w), 0.f);
        nodeEmb[r * 32 + f4] = o;
        if (g != curg) {
            if (curg >= 0) {
                float* p = gsum + (long)curg * D + f4 * 4;
                atomicAdd(p + 0, run.x); atomicAdd(p + 1, run.y);
                atomicAdd(p + 2, run.z); atomicAdd(p + 3, run.w);
            }
            curg = g;
            run = o;
        } else {
            run.x += o.x; run.y += o.y; run.z += o.z; run.w += o.w;
        }
    }
    if (curg >= 0) {
        float* p = gsum + (long)curg * D + f4 * 4;
        atomicAdd(p + 0, run.x); atomicAdd(p + 1, run.y);
        atomicAdd(p + 2, run.z); atomicAdd(p + 3, run.w);
    }
}

// Finalize: mean from gsum/goff, write ge, fc(128->2) reduce -> out.
__global__ __launch_bounds__(128) void k_fc(const float* __restrict__ gsum,
                                            const int* __restrict__ goff,
                                            const float* __restrict__ fcW,
                                            const float* __restrict__ fcb,
                                            float* __restrict__ ge,
                                            float* __restrict__ out) {
    __shared__ float r0[128], r1[128];
    int g = blockIdx.x, j = threadIdx.x;
    int cnt = goff[g + 1] - goff[g];
    float mean = gsum[(long)g * D + j] / (float)(cnt > 0 ? cnt : 1);
    ge[(long)g * D + j] = mean;
    r0[j] = mean * fcW[j * 2 + 0];
    r1[j] = mean * fcW[j * 2 + 1];
    __syncthreads();
    for (int st = 64; st > 0; st >>= 1) {
        if (j < st) { r0[j] += r0[j + st]; r1[j] += r1[j + st]; }
        __syncthreads();
    }
    if (j == 0) {
        out[g * 2 + 0] = r0[0] + fcb[0];
        out[g * 2 + 1] = r1[0] + fcb[1];
    }
}

// ---------------------------------------------------------------------------
extern "C" void kernel_launch(void* const* d_in, const int* in_sizes, int n_in,
                              void* d_out, int out_size, void* d_ws, size_t ws_size,
                              hipStream_t stream) {
    const float* x   = (const float*)d_in[0];
    const int*   ei  = (const int*)d_in[1];
    const int*   bat = (const int*)d_in[2];
    const float* W1  = (const float*)d_in[3];
    const float* b1  = (const float*)d_in[4];
    const float* g1  = (const float*)d_in[5];
    const float* bt1 = (const float*)d_in[6];
    const float* W2  = (const float*)d_in[7];
    const float* b2  = (const float*)d_in[8];
    const float* g2  = (const float*)d_in[9];
    const float* go  = (const float*)d_in[11];
    const float* bo  = (const float*)d_in[12];
    const float* fcW = (const float*)d_in[13];
    const float* fcb = (const float*)d_in[14];

    const long ND = (long)NN * D;
    float* H = (float*)d_ws;
    float* G = H + ND;
    float* S = G + ND;
    float* sum      = S;                       // 128
    float* sq       = S + 128;                 // 128
    float* gsum     = S + 256;                 // NG*D = 65536
    float* biasFall = S + 65792;               // NL*D = 384
    float* affA     = S + 66176;               // 128
    float* affB     = S + 66304;               // 128
    float* W2s      = S + 66432;               // 16384
    int*   goff     = (int*)(S + 82816);       // NG+1
    int*   off      = (int*)(S + 83840);       // NN+1
    int*   srcs     = off + (NN + 1);          // NE

    float* nodeEmb = (float*)d_out;     // also GEMM1 scratch Y
    float* ge   = nodeEmb + ND;
    float* out2 = ge + (long)NG * D;
    float* Y = nodeEmb;

    // CSR-build temporaries alias into nodeEmb (consumed before first GEMM)
    int* deg  = (int*)nodeEmb;
    int* excl = deg + NN;
    int* cur  = excl + NN;
    int* bsum = cur + NN;

    const int edgeGrid = (NE + 255) / 256;
    const int nodeGrid = (NN + 255) / 256;
    const int gathGrid = (int)(((long)NN * 32 + 255) / 256);
    const int gemmGrid = (NN + BM - 1) / BM;     // 782
    const int apGrid   = (NN + 63) / 64;         // 1563

    hipMemsetAsync(deg, 0, NN * sizeof(int), stream);
    k_hist<<<edgeGrid, 256, 0, stream>>>(ei, deg);
    k_scan1<<<nodeGrid, 256, 0, stream>>>(deg, excl, bsum);
    k_scan2<<<1, 512, 0, stream>>>(bsum, nodeGrid);
    k_scan3<<<nodeGrid, 256, 0, stream>>>(excl, bsum, off, cur);
    k_fill<<<edgeGrid, 256, 0, stream>>>(ei, cur, srcs);

    // zero sum/sq/gsum in one shot; k_fold/k_fin2 re-zero sum/sq per GEMM
    hipMemsetAsync(sum, 0, (256 + (long)NG * D) * sizeof(float), stream);
    k_goff<<<nodeGrid, 256, 0, stream>>>(bat, goff, b2, biasFall);

    for (int l = 0; l < NL; ++l) {
        if (l == 0)
            k_gather<<<gathGrid, 256, 0, stream>>>((const float4*)x, off, srcs,
                                                   (float4*)G);
        else
            k_gather_aff<<<gathGrid, 256, 0, stream>>>((const float4*)G, off, srcs,
                                                       affA, affB, (float4*)H);
        const float* gin = (l == 0) ? G : H;

        k_gemm<<<gemmGrid, 256, 0, stream>>>(gin, W1 + (long)l * D * D, b1 + l * D,
                                             Y, sum, sq);
        k_fold<<<128, 128, 0, stream>>>(W2 + (long)l * D * D, sum, sq,
                                        g1 + l * D, bt1 + l * D, W2s,
                                        biasFall + (long)l * D);

        k_gemm<<<gemmGrid, 256, 0, stream>>>(Y, W2s, biasFall + (long)l * D,
                                             G, sum, sq);
        k_fin2<<<1, 128, 0, stream>>>(sum, sq, g2 + l * D, go + l * D, bo + l * D,
                                      affA, affB);
    }

    k_affine_pool<<<apGrid, 256, 0, stream>>>((const float4*)G, affA, affB, bat,
                                              (float4*)nodeEmb, gsum);
    k_fc<<<NG, 128, 0, stream>>>(gsum, goff, fcW, fcb, ge, out2);
}

// Round 13
// 831.334 us; speedup vs baseline: 1.4726x; 1.2192x over previous
//
#include <hip/hip_runtime.h>

#define NN 100000
#define NE 600000
#define NG 512
#define D 128
#define NL 3
#define EPS 1e-5f

typedef unsigned short u16;
typedef __attribute__((ext_vector_type(8))) short bf16x8;
typedef __attribute__((ext_vector_type(4))) float f32x4;

__device__ __forceinline__ u16 f2bf(float x) {
    unsigned u = __float_as_uint(x);
    u = u + 0x7FFFu + ((u >> 16) & 1u);   // RNE
    return (u16)(u >> 16);
}
__device__ __forceinline__ float bf2f(u16 h) {
    return __uint_as_float(((unsigned)h) << 16);
}

// ---------------------------------------------------------------------------
// CSR build: histogram -> exclusive scan -> fill (sorted-by-dst source list)
// ---------------------------------------------------------------------------
__global__ __launch_bounds__(256) void k_hist(const int* __restrict__ ei,
                                              int* __restrict__ deg) {
    int e = blockIdx.x * 256 + threadIdx.x;
    if (e < NE) atomicAdd(&deg[ei[NE + e]], 1);
}

__global__ __launch_bounds__(256) void k_scan1(const int* __restrict__ deg,
                                               int* __restrict__ excl,
                                               int* __restrict__ bsum) {
    __shared__ int s[256];
    int i = blockIdx.x * 256 + threadIdx.x;
    int v = (i < NN) ? deg[i] : 0;
    s[threadIdx.x] = v;
    __syncthreads();
    #pragma unroll
    for (int st = 1; st < 256; st <<= 1) {
        int t = (threadIdx.x >= st) ? s[threadIdx.x - st] : 0;
        __syncthreads();
        s[threadIdx.x] += t;
        __syncthreads();
    }
    if (i < NN) excl[i] = s[threadIdx.x] - v;
    if (threadIdx.x == 255) bsum[blockIdx.x] = s[255];
}

__global__ __launch_bounds__(512) void k_scan2(int* __restrict__ bsum, int nb) {
    __shared__ int s[512];
    int v = (threadIdx.x < nb) ? bsum[threadIdx.x] : 0;
    s[threadIdx.x] = v;
    __syncthreads();
    #pragma unroll
    for (int st = 1; st < 512; st <<= 1) {
        int t = (threadIdx.x >= st) ? s[threadIdx.x - st] : 0;
        __syncthreads();
        s[threadIdx.x] += t;
        __syncthreads();
    }
    if (threadIdx.x < nb) bsum[threadIdx.x] = s[threadIdx.x] - v;  // exclusive
}

__global__ __launch_bounds__(256) void k_scan3(const int* __restrict__ excl,
                                               const int* __restrict__ bsum,
                                               int* __restrict__ off,
                                               int* __restrict__ cur) {
    int i = blockIdx.x * 256 + threadIdx.x;
    if (i < NN) {
        int o = excl[i] + bsum[blockIdx.x];
        off[i] = o;
        cur[i] = o;
    }
    if (i == 0) off[NN] = NE;
}

__global__ __launch_bounds__(256) void k_fill(const int* __restrict__ ei,
                                              int* __restrict__ cur,
                                              int* __restrict__ srcs) {
    int e = blockIdx.x * 256 + threadIdx.x;
    if (e < NE) {
        int d = ei[NE + e];
        int p = atomicAdd(&cur[d], 1);
        srcs[p] = ei[e];
    }
}

// ---------------------------------------------------------------------------
// Graph offsets from sorted batch (boundary scan) + per-layer biasF init.
// ---------------------------------------------------------------------------
__global__ __launch_bounds__(256) void k_goff(const int* __restrict__ batch,
                                              int* __restrict__ goff,
                                              const float* __restrict__ b2all,
                                              float* __restrict__ biasFall) {
    int i = blockIdx.x * 256 + threadIdx.x;
    if (blockIdx.x == 0) {
        for (int j = threadIdx.x; j < NL * D; j += 256) biasFall[j] = b2all[j];
    }
    if (i == 0) {
        int b0 = batch[0];
        for (int g = 0; g <= b0; ++g) goff[g] = 0;
    }
    if (i < NN - 1) {
        int b = batch[i], bn = batch[i + 1];
        for (int g = b + 1; g <= bn; ++g) goff[g] = i + 1;
    }
    if (i == NN - 1) {
        int b = batch[NN - 1];
        for (int g = b + 1; g <= NG; ++g) goff[g] = NN;
    }
}

// W1 -> transposed bf16 hi/lo planes, all 3 layers. Wt[l][j][k] = W1[l][k][j].
__global__ __launch_bounds__(128) void k_wcvt(const float* __restrict__ W1,
                                              u16* __restrict__ Wth,
                                              u16* __restrict__ Wtl) {
    int b = blockIdx.x;          // 0..383
    int l = b >> 7, k = b & 127;
    int j = threadIdx.x;
    float w = W1[(long)l * 16384 + (long)k * 128 + j];
    u16 h = f2bf(w);
    Wth[(long)l * 16384 + (long)j * 128 + k] = h;
    Wtl[(long)l * 16384 + (long)j * 128 + k] = f2bf(w - bf2f(h));
}

// ---------------------------------------------------------------------------
// Gather aggregation (layer 0): acc = x[n] + sum_{s} x[s]; emit bf16 hi/lo.
// ---------------------------------------------------------------------------
__global__ __launch_bounds__(256) void k_gather(const float4* __restrict__ hin,
                                                const int* __restrict__ off,
                                                const int* __restrict__ srcs,
                                                u16* __restrict__ Ahi,
                                                u16* __restrict__ Alo) {
    int t = blockIdx.x * 256 + threadIdx.x;
    int n = t >> 5;
    if (n >= NN) return;
    int f4 = t & 31;
    int lo = off[n], hi = off[n + 1];
    float4 acc = hin[(long)n * 32 + f4];
    for (int e = lo; e < hi; ++e) {
        int s = srcs[e];
        float4 v = hin[(long)s * 32 + f4];
        acc.x += v.x; acc.y += v.y; acc.z += v.z; acc.w += v.w;
    }
    u16 hx = f2bf(acc.x), hy = f2bf(acc.y), hz = f2bf(acc.z), hw = f2bf(acc.w);
    u16 lx = f2bf(acc.x - bf2f(hx)), ly = f2bf(acc.y - bf2f(hy));
    u16 lz = f2bf(acc.z - bf2f(hz)), lw = f2bf(acc.w - bf2f(hw));
    *(ushort4*)(Ahi + (long)n * 128 + f4 * 4) = make_ushort4(hx, hy, hz, hw);
    *(ushort4*)(Alo + (long)n * 128 + f4 * 4) = make_ushort4(lx, ly, lz, lw);
}

// Gather with fused affine+ReLU (layers 1,2); emit bf16 hi/lo planes.
__global__ __launch_bounds__(256) void k_gather_aff(const float4* __restrict__ yin,
                                                    const int* __restrict__ off,
                                                    const int* __restrict__ srcs,
                                                    const float* __restrict__ affA,
                                                    const float* __restrict__ affB,
                                                    u16* __restrict__ Ahi,
                                                    u16* __restrict__ Alo) {
    int t = blockIdx.x * 256 + threadIdx.x;
    int n = t >> 5;
    if (n >= NN) return;
    int f4 = t & 31;
    float4 A = *(const float4*)(affA + f4 * 4);
    float4 B = *(const float4*)(affB + f4 * 4);
    int lo = off[n], hi = off[n + 1];
    float4 v = yin[(long)n * 32 + f4];
    float4 acc;
    acc.x = fmaxf(fmaf(v.x, A.x, B.x), 0.f);
    acc.y = fmaxf(fmaf(v.y, A.y, B.y), 0.f);
    acc.z = fmaxf(fmaf(v.z, A.z, B.z), 0.f);
    acc.w = fmaxf(fmaf(v.w, A.w, B.w), 0.f);
    for (int e = lo; e < hi; ++e) {
        int s = srcs[e];
        float4 u = yin[(long)s * 32 + f4];
        acc.x += fmaxf(fmaf(u.x, A.x, B.x), 0.f);
        acc.y += fmaxf(fmaf(u.y, A.y, B.y), 0.f);
        acc.z += fmaxf(fmaf(u.z, A.z, B.z), 0.f);
        acc.w += fmaxf(fmaf(u.w, A.w, B.w), 0.f);
    }
    u16 hx = f2bf(acc.x), hy = f2bf(acc.y), hz = f2bf(acc.z), hw = f2bf(acc.w);
    u16 lx = f2bf(acc.x - bf2f(hx)), ly = f2bf(acc.y - bf2f(hy));
    u16 lz = f2bf(acc.z - bf2f(hz)), lw = f2bf(acc.w - bf2f(hw));
    *(ushort4*)(Ahi + (long)n * 128 + f4 * 4) = make_ushort4(hx, hy, hz, hw);
    *(ushort4*)(Alo + (long)n * 128 + f4 * 4) = make_ushort4(lx, ly, lz, lw);
}

// ---------------------------------------------------------------------------
// bf16x3 MFMA GEMM + fused column stats. 128 thr = 2 waves; wave owns 16 rows
// x 128 cols (8 col-tiles of 16x16x32 mfma). No LDS staging: A-frags from
// hi/lo planes (16B/lane contiguous), B-frags from transposed W planes (64KB,
// L1/L2-resident). acc = hi*hi + hi*lo + lo*hi (fp32 accumulate).
// Layouts [m89/m91-verified]: A row=lane&15,k=(lane>>4)*8+j; B col=lane&15,
// same k; C/D col=lane&15,row=(lane>>4)*4+reg. NN=6250*16: no tail, no guards.
// Stats: per-ct shfl_xor(16,32) -> LDS[2][128] -> 2 atomics/col into 8 slabs.
// MODE 0: write Y as bf16 hi/lo planes (GEMM2 input). MODE 1: write fp32 G.
// ---------------------------------------------------------------------------
template <int MODE>
__global__ __launch_bounds__(128) void k_gemm_bf3(const u16* __restrict__ Ahi,
                                                  const u16* __restrict__ Alo,
                                                  const u16* __restrict__ Bth,
                                                  const u16* __restrict__ Btl,
                                                  const float* __restrict__ bias,
                                                  u16* __restrict__ Yhi,
                                                  u16* __restrict__ Ylo,
                                                  float* __restrict__ Gout,
                                                  float* __restrict__ slab) {
    __shared__ float ls[2][128], lq[2][128];
    const int tid = threadIdx.x;
    const int wid = tid >> 6, lane = tid & 63;
    const int rmod = lane & 15, kgrp = lane >> 4;
    const long base = ((long)blockIdx.x * 2 + wid) * 16;
    const long arow = base + rmod;

    f32x4 acc[8];
    #pragma unroll
    for (int c = 0; c < 8; ++c) acc[c] = (f32x4){0.f, 0.f, 0.f, 0.f};

    #pragma unroll
    for (int kt = 0; kt < 4; ++kt) {
        const int koff = kt * 32 + kgrp * 8;
        bf16x8 ah = *(const bf16x8*)(Ahi + arow * 128 + koff);
        bf16x8 al = *(const bf16x8*)(Alo + arow * 128 + koff);
        #pragma unroll
        for (int ct = 0; ct < 8; ++ct) {
            const long boff = (long)(ct * 16 + rmod) * 128 + koff;
            bf16x8 bh = *(const bf16x8*)(Bth + boff);
            bf16x8 bl = *(const bf16x8*)(Btl + boff);
            acc[ct] = __builtin_amdgcn_mfma_f32_16x16x32_bf16(ah, bh, acc[ct], 0, 0, 0);
            acc[ct] = __builtin_amdgcn_mfma_f32_16x16x32_bf16(ah, bl, acc[ct], 0, 0, 0);
            acc[ct] = __builtin_amdgcn_mfma_f32_16x16x32_bf16(al, bh, acc[ct], 0, 0, 0);
        }
    }

    #pragma unroll
    for (int ct = 0; ct < 8; ++ct) {
        int col = ct * 16 + rmod;
        float bv = bias[col];
        float s = 0.f, q = 0.f;
        #pragma unroll
        for (int r = 0; r < 4; ++r) {
            float o = acc[ct][r] + bv;
            s += o;
            q += o * o;
            long row = base + kgrp * 4 + r;
            if (MODE == 0) {
                u16 h = f2bf(o);
                Yhi[row * 128 + col] = h;
                Ylo[row * 128 + col] = f2bf(o - bf2f(h));
            } else {
                Gout[row * 128 + col] = o;
            }
        }
        s += __shfl_xor(s, 16);
        s += __shfl_xor(s, 32);
        q += __shfl_xor(q, 16);
        q += __shfl_xor(q, 32);
        if (kgrp == 0) { ls[wid][col] = s; lq[wid][col] = q; }
    }
    __syncthreads();
    {
        float s = ls[0][tid] + ls[1][tid];
        float q = lq[0][tid] + lq[1][tid];
        float* sp = slab + (blockIdx.x & 7) * 256;
        atomicAdd(sp + tid, s);
        atomicAdd(sp + 128 + tid, q);
    }
}

// ---------------------------------------------------------------------------
// BN1-finalize + fold into GEMM2 operands. Emits transposed bf16 hi/lo W2s
// planes + biasF (fp32, pre-init b2). Zeroes its slab entries for GEMM2.
// ---------------------------------------------------------------------------
__global__ __launch_bounds__(128) void k_fold(const float* __restrict__ W2,
                                              float* __restrict__ slab,
                                              const float* __restrict__ g1,
                                              const float* __restrict__ bt1,
                                              u16* __restrict__ Wth,
                                              u16* __restrict__ Wtl,
                                              float* __restrict__ biasF) {
    int k = blockIdx.x, j = threadIdx.x;
    float ms = 0.f, mq = 0.f;
    #pragma unroll
    for (int s2 = 0; s2 < 8; ++s2) {
        ms += slab[s2 * 256 + k];
        mq += slab[s2 * 256 + 128 + k];
    }
    float m = ms * (1.f / NN);
    float v = mq * (1.f / NN) - m * m;
    float a = g1[k] * rsqrtf(v + EPS);
    float c = bt1[k] - m * a;
    float w = W2[(long)k * 128 + j];
    float ws2 = a * w;
    u16 h = f2bf(ws2);
    Wth[(long)j * 128 + k] = h;
    Wtl[(long)j * 128 + k] = f2bf(ws2 - bf2f(h));
    atomicAdd(biasF + j, c * w);
    __syncthreads();
    if (j < 8) { slab[j * 256 + k] = 0.f; slab[j * 256 + 128 + k] = 0.f; }
}

// BN2 + outer BN collapse: A = rs2*g2*rso*go, B = bo - m2*A. Zeroes slabs.
__global__ void k_fin2(float* __restrict__ slab,
                       const float* __restrict__ g2, const float* __restrict__ go,
                       const float* __restrict__ bo, float* __restrict__ affA,
                       float* __restrict__ affB) {
    int f = threadIdx.x;
    float ms = 0.f, mq = 0.f;
    #pragma unroll
    for (int s2 = 0; s2 < 8; ++s2) {
        ms += slab[s2 * 256 + f];
        mq += slab[s2 * 256 + 128 + f];
        slab[s2 * 256 + f] = 0.f;
        slab[s2 * 256 + 128 + f] = 0.f;
    }
    float m = ms * (1.f / NN);
    float v = mq * (1.f / NN) - m * m;
    float t = g2[f] * rsqrtf(v + EPS);
    float vo = t * t * v;
    float Aa = t * rsqrtf(vo + EPS) * go[f];
    affA[f] = Aa;
    affB[f] = bo[f] - m * Aa;
}

// ---------------------------------------------------------------------------
// Final-layer affine+ReLU fused with per-graph sum accumulation.
// ---------------------------------------------------------------------------
__global__ __launch_bounds__(256) void k_affine_pool(const float4* __restrict__ Y,
                                                     const float* __restrict__ affA,
                                                     const float* __restrict__ affB,
                                                     const int* __restrict__ batch,
                                                     float4* __restrict__ nodeEmb,
                                                     float* __restrict__ gsum) {
    int tid = threadIdx.x;
    int f4 = tid & 31;
    int rg = tid >> 5;
    long base = (long)blockIdx.x * 64 + (long)rg * 8;
    float4 A = *(const float4*)(affA + f4 * 4);
    float4 B = *(const float4*)(affB + f4 * 4);
    float4 run = make_float4(0.f, 0.f, 0.f, 0.f);
    int curg = -1;
    #pragma unroll
    for (int i = 0; i < 8; ++i) {
        long r = base + i;
        if (r >= NN) break;
        int g = batch[r];
        float4 v = Y[r * 32 + f4];
        float4 o;
        o.x = fmaxf(fmaf(v.x, A.x, B.x), 0.f);
        o.y = fmaxf(fmaf(v.y, A.y, B.y), 0.f);
        o.z = fmaxf(fmaf(v.z, A.z, B.z), 0.f);
        o.w = fmaxf(fmaf(v.w, A.w, B.w), 0.f);
        nodeEmb[r * 32 + f4] = o;
        if (g != curg) {
            if (curg >= 0) {
                float* p = gsum + (long)curg * D + f4 * 4;
                atomicAdd(p + 0, run.x); atomicAdd(p + 1, run.y);
                atomicAdd(p + 2, run.z); atomicAdd(p + 3, run.w);
            }
            curg = g;
            run = o;
        } else {
            run.x += o.x; run.y += o.y; run.z += o.z; run.w += o.w;
        }
    }
    if (curg >= 0) {
        float* p = gsum + (long)curg * D + f4 * 4;
        atomicAdd(p + 0, run.x); atomicAdd(p + 1, run.y);
        atomicAdd(p + 2, run.z); atomicAdd(p + 3, run.w);
    }
}

// Finalize: mean from gsum/goff, write ge, fc(128->2) reduce -> out.
__global__ __launch_bounds__(128) void k_fc(const float* __restrict__ gsum,
                                            const int* __restrict__ goff,
                                            const float* __restrict__ fcW,
                                            const float* __restrict__ fcb,
                                            float* __restrict__ ge,
                                            float* __restrict__ out) {
    __shared__ float r0[128], r1[128];
    int g = blockIdx.x, j = threadIdx.x;
    int cnt = goff[g + 1] - goff[g];
    float mean = gsum[(long)g * D + j] / (float)(cnt > 0 ? cnt : 1);
    ge[(long)g * D + j] = mean;
    r0[j] = mean * fcW[j * 2 + 0];
    r1[j] = mean * fcW[j * 2 + 1];
    __syncthreads();
    for (int st = 64; st > 0; st >>= 1) {
        if (j < st) { r0[j] += r0[j + st]; r1[j] += r1[j + st]; }
        __syncthreads();
    }
    if (j == 0) {
        out[g * 2 + 0] = r0[0] + fcb[0];
        out[g * 2 + 1] = r1[0] + fcb[1];
    }
}

// ---------------------------------------------------------------------------
extern "C" void kernel_launch(void* const* d_in, const int* in_sizes, int n_in,
                              void* d_out, int out_size, void* d_ws, size_t ws_size,
                              hipStream_t stream) {
    const float* x   = (const float*)d_in[0];
    const int*   ei  = (const int*)d_in[1];
    const int*   bat = (const int*)d_in[2];
    const float* W1  = (const float*)d_in[3];
    const float* b1  = (const float*)d_in[4];
    const float* g1  = (const float*)d_in[5];
    const float* bt1 = (const float*)d_in[6];
    const float* W2  = (const float*)d_in[7];
    const float* b2  = (const float*)d_in[8];
    const float* g2  = (const float*)d_in[9];
    const float* go  = (const float*)d_in[11];
    const float* bo  = (const float*)d_in[12];
    const float* fcW = (const float*)d_in[13];
    const float* fcb = (const float*)d_in[14];

    const long ND = (long)NN * D;
    float* ws = (float*)d_ws;
    float* G   = ws;                      // ND fp32 (GEMM2 out / gather_aff in)
    u16*   Ahi = (u16*)(ws + ND);         // ND bf16 (gather out / GEMM1 in)
    u16*   Alo = Ahi + ND;                // ND bf16
    float* S   = ws + 2 * ND;
    float* slab     = S;                  // 8*256 stats slabs
    float* gsum     = S + 2048;           // NG*D
    float* biasFall = S + 67584;          // NL*D
    float* affA     = S + 67968;          // 128
    float* affB     = S + 68096;          // 128
    int*   goff     = (int*)(S + 68224);  // NG+1 (514 slots)
    u16*   W1tHi    = (u16*)(S + 68740);  // 3*16384 ush
    u16*   W1tLo    = (u16*)(S + 93316);  // 3*16384 ush
    u16*   W2tHi    = (u16*)(S + 117892); // 16384 ush
    u16*   W2tLo    = (u16*)(S + 126084); // 16384 ush
    int*   off      = (int*)(S + 134276); // NN+1
    int*   srcs     = off + (NN + 1);     // NE

    float* nodeEmb = (float*)d_out;
    u16*   Yhi = (u16*)d_out;             // GEMM1 out planes live in d_out
    u16*   Ylo = Yhi + ND;                //   (dead before nodeEmb is written)
    float* ge   = nodeEmb + ND;
    float* out2 = ge + (long)NG * D;

    // CSR-build temporaries alias into d_out (consumed before first GEMM)
    int* deg  = (int*)d_out;
    int* excl = deg + NN;
    int* cur  = excl + NN;
    int* bsum = cur + NN;

    const int edgeGrid = (NE + 255) / 256;
    const int nodeGrid = (NN + 255) / 256;
    const int gathGrid = (int)(((long)NN * 32 + 255) / 256);  // 12500
    const int gemmGrid = NN / 32;                             // 3125 (2 waves/blk)

    hipMemsetAsync(deg, 0, NN * sizeof(int), stream);
    k_hist<<<edgeGrid, 256, 0, stream>>>(ei, deg);
    k_scan1<<<nodeGrid, 256, 0, stream>>>(deg, excl, bsum);
    k_scan2<<<1, 512, 0, stream>>>(bsum, nodeGrid);
    k_scan3<<<nodeGrid, 256, 0, stream>>>(excl, bsum, off, cur);
    k_fill<<<edgeGrid, 256, 0, stream>>>(ei, cur, srcs);

    // zero stats slabs + gsum once; k_fold/k_fin2 re-zero slabs per GEMM
    hipMemsetAsync(slab, 0, (2048 + (long)NG * D) * sizeof(float), stream);
    k_goff<<<nodeGrid, 256, 0, stream>>>(bat, goff, b2, biasFall);
    k_wcvt<<<NL * 128, 128, 0, stream>>>(W1, W1tHi, W1tLo);

    for (int l = 0; l < NL; ++l) {
        if (l == 0)
            k_gather<<<gathGrid, 256, 0, stream>>>((const float4*)x, off, srcs,
                                                   Ahi, Alo);
        else
            k_gather_aff<<<gathGrid, 256, 0, stream>>>((const float4*)G, off, srcs,
                                                       affA, affB, Ahi, Alo);

        k_gemm_bf3<0><<<gemmGrid, 128, 0, stream>>>(
            Ahi, Alo, W1tHi + (long)l * 16384, W1tLo + (long)l * 16384,
            b1 + l * D, Yhi, Ylo, nullptr, slab);

        k_fold<<<128, 128, 0, stream>>>(W2 + (long)l * D * D, slab,
                                        g1 + l * D, bt1 + l * D,
                                        W2tHi, W2tLo, biasFall + (long)l * D);

        k_gemm_bf3<1><<<gemmGrid, 128, 0, stream>>>(
            Yhi, Ylo, W2tHi, W2tLo, biasFall + (long)l * D,
            nullptr, nullptr, G, slab);

        k_fin2<<<1, 128, 0, stream>>>(slab, g2 + l * D, go + l * D, bo + l * D,
                                      affA, affB);
    }

    k_affine_pool<<<(NN + 63) / 64, 256, 0, stream>>>((const float4*)G, affA, affB,
                                                      bat, (float4*)nodeEmb, gsum);
    k_fc<<<NG, 128, 0, stream>>>(gsum, goff, fcW, fcb, ge, out2);
}